// Round 10
// baseline (220.928 us; speedup 1.0000x reference)
//
#include <hip/hip_runtime.h>

// Feature dims fixed by the problem
constexpr int FIN = 64;   // input features
constexpr int FH  = 64;   // hidden
constexpr int FO  = 16;   // output

// edge_index arrives as int32 (harness integer convention), flat [2][E]:
// src = ei[e], dst = ei[e + E].

// Bucket sort parameters: bucket = dst >> 7 (128 nodes per bucket).
constexpr int BSH      = 7;
constexpr int BW       = 1 << BSH;  // 128 nodes / bucket
constexpr int NBUCK    = 1024;      // covers N up to 131072
// ONE chunk size shared by hist and binning. 4096 edges/chunk -> 391 chunks.
constexpr int EPB      = 4096;
// Hierarchical scan: serial single-block section touches only NGRP values
// per bucket (round-5 lesson: single block streaming 4 MB = 46 us).
constexpr int NGRP     = 32;

// GEMM x-tile LDS stride: 68 floats (pad 64+4) so the 4-row-strided compute
// reads alias only 2-way on banks (2-way is free on CDNA4).
constexpr int XSTR     = 68;

// bf16 helpers (manual RNE; exact expand)
__device__ inline unsigned short f2bf(float f) {
    unsigned u = __float_as_uint(f);
    return (unsigned short)((u + 0x7FFFu + ((u >> 16) & 1u)) >> 16);
}
__device__ inline float bf2f(unsigned short h) {
    return __uint_as_float((unsigned)h << 16);
}
__device__ inline float4 bf4_to_f4(ushort4 u) {
    float4 f;
    f.x = bf2f(u.x); f.y = bf2f(u.y); f.z = bf2f(u.z); f.w = bf2f(u.w);
    return f;
}

// ---------------------------------------------------------------------------
// Kernel: dst-bucket histogram. One block per 4K-edge chunk; 8-deep batched
// loads then 8 LDS-atomic chains. Stores only the per-chunk hist (ushort).
// ---------------------------------------------------------------------------
__launch_bounds__(256)
__global__ void hist_kernel(const int* __restrict__ ei, int E,
                            unsigned short* __restrict__ gchist) {
    __shared__ int lh[NBUCK];
    int t = threadIdx.x;
    for (int i = t; i < NBUCK; i += 256) lh[i] = 0;
    __syncthreads();
    int base = blockIdx.x * EPB;
    int lim  = min(E, base + EPB);
    for (int e0 = base + t; e0 < lim; e0 += 2048) {
        int dd[8];
        #pragma unroll
        for (int q = 0; q < 8; ++q) {
            int e = e0 + q * 256;
            dd[q] = (e < lim) ? ei[E + e] : -1;
        }
        #pragma unroll
        for (int q = 0; q < 8; ++q)
            if (dd[q] >= 0) atomicAdd(&lh[dd[q] >> BSH], 1);
    }
    __syncthreads();
    unsigned short* gh = gchist + (size_t)blockIdx.x * NBUCK;
    for (int b = t; b < NBUCK; b += 256)
        gh[b] = (unsigned short)lh[b];              // c <= EPB=4096, fits ushort
}

// ---------------------------------------------------------------------------
// Kernel: per-(group,bucket) partial sums. Grid = NGRP * (NBUCK/256).
// ---------------------------------------------------------------------------
__launch_bounds__(256)
__global__ void group_sum_kernel(const unsigned short* __restrict__ gchist,
                                 int* __restrict__ psum, int NCH, int CPG) {
    int g  = blockIdx.x >> 2;                       // group
    int br = ((blockIdx.x & 3) << 8) + threadIdx.x; // bucket
    int c0 = g * CPG, c1 = min(NCH, c0 + CPG);
    int s = 0;
    #pragma unroll 4
    for (int c = c0; c < c1; ++c)
        s += (int)gchist[(size_t)c * NBUCK + br];
    psum[(size_t)g * NBUCK + br] = s;
}

// ---------------------------------------------------------------------------
// Kernel: single-block scan over buckets + groups (NGRP values per bucket).
// ---------------------------------------------------------------------------
__launch_bounds__(1024)
__global__ void bucket_scan_kernel(const int* __restrict__ psum,
                                   int* __restrict__ bbase,
                                   int* __restrict__ gbase_grp,
                                   int* __restrict__ offs, int N, int E) {
    __shared__ int s[NBUCK];
    int t = threadIdx.x;
    int v = 0;
    #pragma unroll
    for (int g = 0; g < NGRP; ++g)
        v += psum[(size_t)g * NBUCK + t];
    s[t] = v;
    __syncthreads();
    for (int d = 1; d < NBUCK; d <<= 1) {
        int u = (t >= d) ? s[t - d] : 0;
        __syncthreads();
        s[t] += u;
        __syncthreads();
    }
    int ex = s[t] - v;
    bbase[t] = ex;
    if (t == NBUCK - 1) {
        bbase[NBUCK] = s[t];   // == E
        offs[N] = E;
    }
    int run = ex;
    #pragma unroll
    for (int g = 0; g < NGRP; ++g) {
        gbase_grp[(size_t)g * NBUCK + t] = run;
        run += psum[(size_t)g * NBUCK + t];
    }
}

// ---------------------------------------------------------------------------
// Kernel: per-(chunk,bucket) write bases within each group.
// ---------------------------------------------------------------------------
__launch_bounds__(256)
__global__ void chunk_base_kernel(const unsigned short* __restrict__ gchist,
                                  const int* __restrict__ gbase_grp,
                                  int* __restrict__ gbase, int NCH, int CPG) {
    int g  = blockIdx.x >> 2;
    int br = ((blockIdx.x & 3) << 8) + threadIdx.x;
    int c0 = g * CPG, c1 = min(NCH, c0 + CPG);
    int run = gbase_grp[(size_t)g * NBUCK + br];
    #pragma unroll 4
    for (int c = c0; c < c1; ++c) {
        gbase[(size_t)c * NBUCK + br] = run;
        run += (int)gchist[(size_t)c * NBUCK + br];
    }
}

// ---------------------------------------------------------------------------
// Binning device body: cursor row precomputed from gbase -> single pass,
// LDS atomics only. 8-deep batched. Packed word: src | (dst&127)<<17.
// ---------------------------------------------------------------------------
__device__ inline void binning_body(const int* __restrict__ ei, int E, int chunk,
                                    const int* __restrict__ gbase,
                                    unsigned* __restrict__ ebuf, int* lh) {
    int t = threadIdx.x;
    const int* gb = gbase + (size_t)chunk * NBUCK;
    for (int i = t; i < NBUCK; i += 256) lh[i] = gb[i];
    __syncthreads();
    int base = chunk * EPB;
    int lim  = min(E, base + EPB);
    for (int e0 = base + t; e0 < lim; e0 += 2048) {
        int dd[8], ss[8];
        #pragma unroll
        for (int q = 0; q < 8; ++q) {
            int e = e0 + q * 256;
            if (e < lim) { dd[q] = ei[E + e]; ss[q] = ei[e]; } else dd[q] = -1;
        }
        #pragma unroll
        for (int q = 0; q < 8; ++q) {
            if (dd[q] >= 0) {
                int pos = atomicAdd(&lh[dd[q] >> BSH], 1);
                ebuf[pos] = (unsigned)ss[q] | ((unsigned)(dd[q] & (BW - 1)) << 17);
            }
        }
    }
}

__launch_bounds__(256)
__global__ void binning_kernel(const int* __restrict__ ei, int E,
                               const int* __restrict__ gbase, unsigned* __restrict__ ebuf) {
    __shared__ int lh[NBUCK];
    binning_body(ei, E, blockIdx.x, gbase, ebuf, lh);
}

// Per-j FMA block for the GEMM microkernel (all operands in registers).
#define GEMM_JSTEP(WV, J)                                                    \
    {   float v0 = xa0f[J], v1 = xa1f[J], v2 = xa2f[J], v3 = xa3f[J];        \
        acc0.x = fmaf(v0, WV.x, acc0.x); acc0.y = fmaf(v0, WV.y, acc0.y);    \
        acc0.z = fmaf(v0, WV.z, acc0.z); acc0.w = fmaf(v0, WV.w, acc0.w);    \
        acc1.x = fmaf(v1, WV.x, acc1.x); acc1.y = fmaf(v1, WV.y, acc1.y);    \
        acc1.z = fmaf(v1, WV.z, acc1.z); acc1.w = fmaf(v1, WV.w, acc1.w);    \
        acc2.x = fmaf(v2, WV.x, acc2.x); acc2.y = fmaf(v2, WV.y, acc2.y);    \
        acc2.z = fmaf(v2, WV.z, acc2.z); acc2.w = fmaf(v2, WV.w, acc2.w);    \
        acc3.x = fmaf(v3, WV.x, acc3.x); acc3.y = fmaf(v3, WV.y, acc3.y);    \
        acc3.z = fmaf(v3, WV.z, acc3.z); acc3.w = fmaf(v3, WV.w, acc3.w); }

// ---------------------------------------------------------------------------
// Fused kernel: blocks [0, NBIN) bin; blocks [NBIN, NBIN+G1T) do
// hsb = bf16(x @ W1) for TWO 64-row tiles per block (W1 staged once).
// Per kc, all 8 LDS reads are issued into named registers before any FMA.
// ---------------------------------------------------------------------------
__launch_bounds__(256, 4)
__global__ void gemm1_binning_kernel(const float* __restrict__ x, const float* __restrict__ W1,
                                     unsigned short* __restrict__ hsb,
                                     const int* __restrict__ ei, int E,
                                     const int* __restrict__ gbase, unsigned* __restrict__ ebuf,
                                     int N, int NBIN) {
    __shared__ float smem[FIN * FH + 64 * XSTR];   // 33.8 KB: Ws + Xs | lh (4 KB)
    int tid = threadIdx.x;
    if ((int)blockIdx.x < NBIN) {
        binning_body(ei, E, (int)blockIdx.x, gbase, ebuf, (int*)smem);
        return;
    }
    // ---- GEMM phase: two 64-row tiles ----
    float* Ws = smem;                  // [64][64] row-major (k, col)
    float* Xs = smem + FIN * FH;       // [64][XSTR] row-major (row, k), padded
    int rowBase0 = ((int)blockIdx.x - NBIN) * 128;
    {
        const float4* W14 = (const float4*)W1;
        float4* Ws4 = (float4*)Ws;
        #pragma unroll
        for (int i = tid; i < 1024; i += 256) Ws4[i] = W14[i];
    }
    int cg = tid & 15;                 // col group: cols cg*4..+3
    int rg = tid >> 4;                 // row group: rows rg*4..+3
    const float4* x4 = (const float4*)x;
    ushort4* hsb4 = (ushort4*)hsb;
    for (int h = 0; h < 2; ++h) {
        int rowBase = rowBase0 + h * 64;
        if (rowBase >= N) break;                   // uniform across block
        #pragma unroll
        for (int i = tid; i < 1024; i += 256) {
            int row = i >> 4, kq = i & 15;
            int gr = min(rowBase + row, N - 1);    // clamp: loads never fault
            *(float4*)&Xs[row * XSTR + kq * 4] = x4[(size_t)gr * 16 + kq];
        }
        __syncthreads();
        int r0 = rowBase + rg * 4;
        float4 acc0 = {0,0,0,0}, acc1 = {0,0,0,0}, acc2 = {0,0,0,0}, acc3 = {0,0,0,0};
        #pragma unroll 2
        for (int kc = 0; kc < 16; ++kc) {
            // batch all 8 LDS reads first (single waitcnt), then 256 FMAs
            float4 xa0 = *(const float4*)&Xs[(rg * 4 + 0) * XSTR + kc * 4];
            float4 xa1 = *(const float4*)&Xs[(rg * 4 + 1) * XSTR + kc * 4];
            float4 xa2 = *(const float4*)&Xs[(rg * 4 + 2) * XSTR + kc * 4];
            float4 xa3 = *(const float4*)&Xs[(rg * 4 + 3) * XSTR + kc * 4];
            float4 wv0 = *(const float4*)&Ws[(kc * 4 + 0) * FH + cg * 4];
            float4 wv1 = *(const float4*)&Ws[(kc * 4 + 1) * FH + cg * 4];
            float4 wv2 = *(const float4*)&Ws[(kc * 4 + 2) * FH + cg * 4];
            float4 wv3 = *(const float4*)&Ws[(kc * 4 + 3) * FH + cg * 4];
            const float* xa0f = (const float*)&xa0;
            const float* xa1f = (const float*)&xa1;
            const float* xa2f = (const float*)&xa2;
            const float* xa3f = (const float*)&xa3;
            GEMM_JSTEP(wv0, 0)
            GEMM_JSTEP(wv1, 1)
            GEMM_JSTEP(wv2, 2)
            GEMM_JSTEP(wv3, 3)
        }
        if (r0 + 0 < N) hsb4[(size_t)(r0 + 0) * 16 + cg] =
            make_ushort4(f2bf(acc0.x), f2bf(acc0.y), f2bf(acc0.z), f2bf(acc0.w));
        if (r0 + 1 < N) hsb4[(size_t)(r0 + 1) * 16 + cg] =
            make_ushort4(f2bf(acc1.x), f2bf(acc1.y), f2bf(acc1.z), f2bf(acc1.w));
        if (r0 + 2 < N) hsb4[(size_t)(r0 + 2) * 16 + cg] =
            make_ushort4(f2bf(acc2.x), f2bf(acc2.y), f2bf(acc2.z), f2bf(acc2.w));
        if (r0 + 3 < N) hsb4[(size_t)(r0 + 3) * 16 + cg] =
            make_ushort4(f2bf(acc3.x), f2bf(acc3.y), f2bf(acc3.z), f2bf(acc3.w));
        __syncthreads();                           // Xs reusable next tile
    }
}

// ---------------------------------------------------------------------------
// Kernel: per-bucket CSR build + dinv + offs. One block per bucket; 8-deep
// batched passes; all csr stores land in the block's own contiguous region.
// ---------------------------------------------------------------------------
__launch_bounds__(256)
__global__ void bucket_csr_kernel(const unsigned* __restrict__ ebuf,
                                  const int* __restrict__ bbase,
                                  int* __restrict__ csr, int* __restrict__ offs,
                                  float* __restrict__ dinv, int N) {
    __shared__ int cnt[BW], sc[BW], cur[BW];
    int t = threadIdx.x;
    int b = blockIdx.x;
    if (t < BW) cnt[t] = 0;
    __syncthreads();
    int beg = bbase[b], end = bbase[b + 1];
    for (int i0 = beg + t; i0 < end; i0 += 2048) {
        unsigned ww[8];
        #pragma unroll
        for (int q = 0; q < 8; ++q) {
            int i = i0 + q * 256;
            ww[q] = (i < end) ? ebuf[i] : 0xFFFFFFFFu;   // valid entries < 2^24
        }
        #pragma unroll
        for (int q = 0; q < 8; ++q)
            if (ww[q] != 0xFFFFFFFFu) atomicAdd(&cnt[ww[q] >> 17], 1);
    }
    __syncthreads();
    if (t < BW) sc[t] = cnt[t];
    __syncthreads();
    for (int d = 1; d < BW; d <<= 1) {
        int u = (t < BW && t >= d) ? sc[t - d] : 0;
        __syncthreads();
        if (t < BW) sc[t] += u;
        __syncthreads();
    }
    int nodeBase = b << BSH;
    if (t < BW) {
        int node = nodeBase + t;
        int ex = beg + sc[t] - cnt[t];
        cur[t] = ex;
        if (node < N) {
            offs[node] = ex;
            dinv[node] = rsqrtf((float)(cnt[t] + 1));
        }
    }
    __syncthreads();
    for (int i0 = beg + t; i0 < end; i0 += 2048) {
        unsigned ww[8];
        #pragma unroll
        for (int q = 0; q < 8; ++q) {
            int i = i0 + q * 256;
            ww[q] = (i < end) ? ebuf[i] : 0xFFFFFFFFu;
        }
        #pragma unroll
        for (int q = 0; q < 8; ++q) {
            if (ww[q] != 0xFFFFFFFFu) {
                int pos = atomicAdd(&cur[ww[q] >> 17], 1);
                csr[pos] = (int)(ww[q] & 0x1FFFF);
            }
        }
    }
}

// 8-edge gather+accumulate batch for one node's feature chunk.
#define AGG_B8(J, ACC)                                                          \
    {   int s0 = csr[(J)],     s1 = csr[(J) + 1], s2 = csr[(J) + 2], s3 = csr[(J) + 3]; \
        int s4 = csr[(J) + 4], s5 = csr[(J) + 5], s6 = csr[(J) + 6], s7 = csr[(J) + 7]; \
        float d0 = dinv[s0], d1 = dinv[s1], d2 = dinv[s2], d3 = dinv[s3];       \
        float d4 = dinv[s4], d5 = dinv[s5], d6 = dinv[s6], d7 = dinv[s7];       \
        float4 a0 = bf4_to_f4(hs4[(size_t)s0 * 16 + l]);                        \
        float4 a1 = bf4_to_f4(hs4[(size_t)s1 * 16 + l]);                        \
        float4 a2 = bf4_to_f4(hs4[(size_t)s2 * 16 + l]);                        \
        float4 a3 = bf4_to_f4(hs4[(size_t)s3 * 16 + l]);                        \
        float4 a4 = bf4_to_f4(hs4[(size_t)s4 * 16 + l]);                        \
        float4 a5 = bf4_to_f4(hs4[(size_t)s5 * 16 + l]);                        \
        float4 a6 = bf4_to_f4(hs4[(size_t)s6 * 16 + l]);                        \
        float4 a7 = bf4_to_f4(hs4[(size_t)s7 * 16 + l]);                        \
        ACC.x += (fmaf(a0.x, d0, a1.x * d1) + fmaf(a2.x, d2, a3.x * d3))        \
               + (fmaf(a4.x, d4, a5.x * d5) + fmaf(a6.x, d6, a7.x * d7));       \
        ACC.y += (fmaf(a0.y, d0, a1.y * d1) + fmaf(a2.y, d2, a3.y * d3))        \
               + (fmaf(a4.y, d4, a5.y * d5) + fmaf(a6.y, d6, a7.y * d7));       \
        ACC.z += (fmaf(a0.z, d0, a1.z * d1) + fmaf(a2.z, d2, a3.z * d3))        \
               + (fmaf(a4.z, d4, a5.z * d5) + fmaf(a6.z, d6, a7.z * d7));       \
        ACC.w += (fmaf(a0.w, d0, a1.w * d1) + fmaf(a2.w, d2, a3.w * d3))        \
               + (fmaf(a4.w, d4, a5.w * d5) + fmaf(a6.w, d6, a7.w * d7)); }

// ---------------------------------------------------------------------------
// Kernel: layer-1 PULL aggregation fused with finalize1 + GEMM2.
// KEY CHANGE vs round 9: each thread owns feature-chunk l of TWO nodes
// (n and n+16) with fully independent accumulators/cursors, and the common
// case issues BOTH nodes' 8-edge batches back-to-back (16 independent row
// gathers in flight). Rationale: VGPR=36 showed the compiler recycles
// landing registers within ONE dependent chain (R4/R7 failures); two
// independent chains double memory-level parallelism without cross-lane
// traffic (R8's failure mode). 32 nodes/block, GA=3125.
// ---------------------------------------------------------------------------
__launch_bounds__(256)
__global__ void agg1_gemm2_kernel(const unsigned short* __restrict__ hsb,
                                  const int* __restrict__ csr,
                                  const int* __restrict__ offs, const float* __restrict__ dinv,
                                  const float* __restrict__ b1, const float* __restrict__ W2,
                                  unsigned short* __restrict__ hs2b, int N) {
    __shared__ float W2s[FH * FO];       // 4 KB
    __shared__ float h1s[32][68];        // 8.7 KB, non-pow2 row stride
    const ushort4* hs4 = (const ushort4*)hsb;   // 16 ushort4 per row
    int tid = threadIdx.x;
    for (int i = tid; i < FH * FO; i += 256) W2s[i] = W2[i];
    int g = tid >> 4, l = tid & 15;
    int nA = blockIdx.x * 32 + g;
    int nB = nA + 16;
    bool vA = nA < N, vB = nB < N;
    float4 accA = {0,0,0,0}, accB = {0,0,0,0};
    float diA = 0.f, diB = 0.f;
    int jA = 0, eA = 0, jB = 0, eB = 0;
    if (vA) {
        diA = dinv[nA];
        float4 s = bf4_to_f4(hs4[(size_t)nA * 16 + l]);
        accA.x = s.x * diA; accA.y = s.y * diA; accA.z = s.z * diA; accA.w = s.w * diA;
        jA = offs[nA]; eA = offs[nA + 1];
    }
    if (vB) {
        diB = dinv[nB];
        float4 s = bf4_to_f4(hs4[(size_t)nB * 16 + l]);
        accB.x = s.x * diB; accB.y = s.y * diB; accB.z = s.z * diB; accB.w = s.w * diB;
        jB = offs[nB]; eB = offs[nB + 1];
    }
    // dual-chain main loop: both nodes' batches issued together
    while (jA + 7 < eA && jB + 7 < eB) {
        AGG_B8(jA, accA)
        AGG_B8(jB, accB)
        jA += 8; jB += 8;
    }
    for (; jA + 7 < eA; jA += 8) AGG_B8(jA, accA)
    for (; jB + 7 < eB; jB += 8) AGG_B8(jB, accB)
    for (; jA + 1 < eA; jA += 2) {
        int s0 = csr[jA], s1 = csr[jA + 1];
        float d0 = dinv[s0], d1 = dinv[s1];
        float4 a0 = bf4_to_f4(hs4[(size_t)s0 * 16 + l]);
        float4 a1 = bf4_to_f4(hs4[(size_t)s1 * 16 + l]);
        accA.x += fmaf(a0.x, d0, a1.x * d1);
        accA.y += fmaf(a0.y, d0, a1.y * d1);
        accA.z += fmaf(a0.z, d0, a1.z * d1);
        accA.w += fmaf(a0.w, d0, a1.w * d1);
    }
    if (jA < eA) {
        int s0 = csr[jA];
        float d0 = dinv[s0];
        float4 a0 = bf4_to_f4(hs4[(size_t)s0 * 16 + l]);
        accA.x = fmaf(a0.x, d0, accA.x); accA.y = fmaf(a0.y, d0, accA.y);
        accA.z = fmaf(a0.z, d0, accA.z); accA.w = fmaf(a0.w, d0, accA.w);
    }
    for (; jB + 1 < eB; jB += 2) {
        int s0 = csr[jB], s1 = csr[jB + 1];
        float d0 = dinv[s0], d1 = dinv[s1];
        float4 a0 = bf4_to_f4(hs4[(size_t)s0 * 16 + l]);
        float4 a1 = bf4_to_f4(hs4[(size_t)s1 * 16 + l]);
        accB.x += fmaf(a0.x, d0, a1.x * d1);
        accB.y += fmaf(a0.y, d0, a1.y * d1);
        accB.z += fmaf(a0.z, d0, a1.z * d1);
        accB.w += fmaf(a0.w, d0, a1.w * d1);
    }
    if (jB < eB) {
        int s0 = csr[jB];
        float d0 = dinv[s0];
        float4 a0 = bf4_to_f4(hs4[(size_t)s0 * 16 + l]);
        accB.x = fmaf(a0.x, d0, accB.x); accB.y = fmaf(a0.y, d0, accB.y);
        accB.z = fmaf(a0.z, d0, accB.z); accB.w = fmaf(a0.w, d0, accB.w);
    }
    float4 bb = ((const float4*)b1)[l];
    if (vA) {
        float4 h;
        h.x = fmaxf(fmaf(diA, accA.x, bb.x), 0.f);
        h.y = fmaxf(fmaf(diA, accA.y, bb.y), 0.f);
        h.z = fmaxf(fmaf(diA, accA.z, bb.z), 0.f);
        h.w = fmaxf(fmaf(diA, accA.w, bb.w), 0.f);
        *((float4*)&h1s[g][l * 4]) = h;
    }
    if (vB) {
        float4 h;
        h.x = fmaxf(fmaf(diB, accB.x, bb.x), 0.f);
        h.y = fmaxf(fmaf(diB, accB.y, bb.y), 0.f);
        h.z = fmaxf(fmaf(diB, accB.z, bb.z), 0.f);
        h.w = fmaxf(fmaf(diB, accB.w, bb.w), 0.f);
        *((float4*)&h1s[g + 16][l * 4]) = h;
    }
    __syncthreads();
    // GEMM2: 32 rows x 16 out-cols, 2 rows per thread
    int r = tid >> 4, o = tid & 15;
    #pragma unroll
    for (int rr = r; rr < 32; rr += 16) {
        int n2 = blockIdx.x * 32 + rr;
        if (n2 < N) {
            float acc = 0.f;
            #pragma unroll
            for (int jj = 0; jj < FH; ++jj)
                acc = fmaf(h1s[rr][jj], W2s[jj * FO + o], acc);
            hs2b[(size_t)n2 * FO + o] = f2bf(acc * dinv[n2]);   // pre-scaled bf16
        }
    }
}

// ---------------------------------------------------------------------------
// Kernel: layer-2 PULL aggregation (8 gathers in flight) + bias + log_softmax.
// hs2b table is 3.2 MB -> fits per-XCD L2; gathers are 2B/lane.
// ---------------------------------------------------------------------------
__launch_bounds__(256)
__global__ void agg2_softmax_kernel(const unsigned short* __restrict__ hs2b,
                                    const int* __restrict__ csr,
                                    const int* __restrict__ offs, const float* __restrict__ dinv,
                                    const float* __restrict__ b2, float* __restrict__ out, int N) {
    int tid = threadIdx.x;
    int g = tid >> 4, o = tid & 15;
    int n = blockIdx.x * 16 + g;
    float v = 0.f;
    if (n < N) {
        float acc = bf2f(hs2b[(size_t)n * 16 + o]);    // self loop (pre-scaled)
        int j = offs[n], end = offs[n + 1];
        for (; j + 7 < end; j += 8) {
            int s0 = csr[j],     s1 = csr[j + 1], s2 = csr[j + 2], s3 = csr[j + 3];
            int s4 = csr[j + 4], s5 = csr[j + 5], s6 = csr[j + 6], s7 = csr[j + 7];
            float t0 = bf2f(hs2b[(size_t)s0 * 16 + o]) + bf2f(hs2b[(size_t)s1 * 16 + o]);
            float t1 = bf2f(hs2b[(size_t)s2 * 16 + o]) + bf2f(hs2b[(size_t)s3 * 16 + o]);
            float t2 = bf2f(hs2b[(size_t)s4 * 16 + o]) + bf2f(hs2b[(size_t)s5 * 16 + o]);
            float t3 = bf2f(hs2b[(size_t)s6 * 16 + o]) + bf2f(hs2b[(size_t)s7 * 16 + o]);
            acc += (t0 + t1) + (t2 + t3);
        }
        for (; j < end; ++j) acc += bf2f(hs2b[(size_t)csr[j] * 16 + o]);
        v = fmaf(dinv[n], acc, b2[o]);
    }
    float m = v;
    #pragma unroll
    for (int s = 8; s >= 1; s >>= 1) m = fmaxf(m, __shfl_xor(m, s, 64));
    float ex = __expf(v - m);
    float sum = ex;
    #pragma unroll
    for (int s = 8; s >= 1; s >>= 1) sum += __shfl_xor(sum, s, 64);
    if (n < N) out[(size_t)n * FO + o] = v - m - __logf(sum);
}

// ---------------------------------------------------------------------------
extern "C" void kernel_launch(void* const* d_in, const int* in_sizes, int n_in,
                              void* d_out, int out_size, void* d_ws, size_t ws_size,
                              hipStream_t stream) {
    const float* x  = (const float*)d_in[0];
    const int*   ei = (const int*)d_in[1];     // int32
    const float* W1 = (const float*)d_in[2];
    const float* b1 = (const float*)d_in[3];
    const float* W2 = (const float*)d_in[4];
    const float* b2 = (const float*)d_in[5];
    float* out = (float*)d_out;

    const int N = in_sizes[0] / FIN;
    const int E = in_sizes[1] / 2;
    const int NCH  = (E + EPB - 1) / EPB;            // hist/binning chunks
    const int CPG  = (NCH + NGRP - 1) / NGRP;        // chunks per scan-group
    const int NB4  = (N + BW - 1) / BW;              // buckets actually used
    const int G1T  = (N + 127) / 128;                // gemm 128-row (2-tile) blocks
    const int GA1  = (N + 31) / 32;                  // agg1 blocks (32 nodes each)
    const int GA2  = (N + 15) / 16;                  // agg2 blocks

    char* ws = (char*)d_ws;
    size_t off = 0;
    auto alloc = [&](size_t bytes) -> void* {
        off = (off + 255) & ~(size_t)255;
        void* p = ws + off;
        off += bytes;
        return p;
    };
    float*          dinv      = (float*)alloc((size_t)N * 4);               //  0.4 MB
    unsigned short* hsb       = (unsigned short*)alloc((size_t)N * FH * 2); // 12.8 MB
    unsigned short* hs2b      = (unsigned short*)alloc((size_t)N * FO * 2); //  3.2 MB
    int*            offs      = (int*)alloc((size_t)(N + 1) * 4);           //  0.4 MB
    int*            bbase     = (int*)alloc((NBUCK + 1) * 4);
    unsigned short* gchist    = (unsigned short*)alloc((size_t)NCH * NBUCK * 2); // 0.8 MB
    int*            gbase     = (int*)alloc((size_t)NCH * NBUCK * 4);       //  1.6 MB
    int*            psum      = (int*)alloc((size_t)NGRP * NBUCK * 4);      //  128 KB
    int*            gbase_grp = (int*)alloc((size_t)NGRP * NBUCK * 4);      //  128 KB
    // ebuf + csr (2*E ints = 12.8 MB): in ws if it fits, else alias the x
    // input buffer (25.6 MB, dead after the gemm phase; harness restores d_in
    // before every launch; ws_size constant -> capture-stable branch).
    unsigned* ebuf;
    int*      csr;
    bool ws_fits = (ws_size >= off + 512 + (size_t)E * 8);
    if (ws_fits) {
        ebuf = (unsigned*)alloc((size_t)E * 4);
        csr  = (int*)     alloc((size_t)E * 4);
    } else {
        ebuf = (unsigned*)x;
        csr  = (int*)x + E;
    }

    hist_kernel<<<NCH, 256, 0, stream>>>(ei, E, gchist);
    group_sum_kernel<<<NGRP * (NBUCK / 256), 256, 0, stream>>>(gchist, psum, NCH, CPG);
    bucket_scan_kernel<<<1, NBUCK, 0, stream>>>(psum, bbase, gbase_grp, offs, N, E);
    chunk_base_kernel<<<NGRP * (NBUCK / 256), 256, 0, stream>>>(gchist, gbase_grp,
                                                                gbase, NCH, CPG);
    if (ws_fits) {
        // Overlap: binning blocks first, gemm blocks backfill.
        gemm1_binning_kernel<<<NCH + G1T, 256, 0, stream>>>(x, W1, hsb, ei, E,
                                                            gbase, ebuf, N, NCH);
    } else {
        // ebuf aliases x: gemm must fully precede binning.
        gemm1_binning_kernel<<<G1T, 256, 0, stream>>>(x, W1, hsb, ei, E,
                                                      gbase, ebuf, N, 0);
        binning_kernel<<<NCH, 256, 0, stream>>>(ei, E, gbase, ebuf);
    }
    bucket_csr_kernel<<<NB4, 256, 0, stream>>>(ebuf, bbase, csr, offs, dinv, N);
    agg1_gemm2_kernel<<<GA1, 256, 0, stream>>>(hsb, csr, offs, dinv, b1, W2, hs2b, N);
    agg2_softmax_kernel<<<GA2, 256, 0, stream>>>(hs2b, csr, offs, dinv, b2, out, N);
}

// Round 11
// 196.936 us; speedup vs baseline: 1.1218x; 1.1218x over previous
//
#include <hip/hip_runtime.h>

// Feature dims fixed by the problem
constexpr int FIN = 64;   // input features
constexpr int FH  = 64;   // hidden
constexpr int FO  = 16;   // output

// edge_index arrives as int32 (harness integer convention), flat [2][E]:
// src = ei[e], dst = ei[e + E].

// Bucket sort parameters: bucket = dst >> 7 (128 nodes per bucket).
constexpr int BSH      = 7;
constexpr int BW       = 1 << BSH;  // 128 nodes / bucket
constexpr int NBUCK    = 1024;      // covers N up to 131072
// ONE chunk size shared by hist and binning. 4096 edges/chunk -> 391 chunks.
constexpr int EPB      = 4096;
// Hierarchical scan: serial single-block section touches only NGRP values
// per bucket (round-5 lesson: single block streaming 4 MB = 46 us).
constexpr int NGRP     = 32;

// GEMM x-tile LDS stride: 68 floats (pad 64+4) so the 4-row-strided compute
// reads alias only 2-way on banks (2-way is free on CDNA4).
constexpr int XSTR     = 68;

// bf16 helpers (manual RNE; exact expand)
__device__ inline unsigned short f2bf(float f) {
    unsigned u = __float_as_uint(f);
    return (unsigned short)((u + 0x7FFFu + ((u >> 16) & 1u)) >> 16);
}
__device__ inline float bf2f(unsigned short h) {
    return __uint_as_float((unsigned)h << 16);
}
__device__ inline float4 bf4_to_f4(ushort4 u) {
    float4 f;
    f.x = bf2f(u.x); f.y = bf2f(u.y); f.z = bf2f(u.z); f.w = bf2f(u.w);
    return f;
}

// ---------------------------------------------------------------------------
// Kernel: dst-bucket histogram. One block per 4K-edge chunk; 8-deep batched
// loads then 8 LDS-atomic chains. Stores only the per-chunk hist (ushort).
// ---------------------------------------------------------------------------
__launch_bounds__(256)
__global__ void hist_kernel(const int* __restrict__ ei, int E,
                            unsigned short* __restrict__ gchist) {
    __shared__ int lh[NBUCK];
    int t = threadIdx.x;
    for (int i = t; i < NBUCK; i += 256) lh[i] = 0;
    __syncthreads();
    int base = blockIdx.x * EPB;
    int lim  = min(E, base + EPB);
    for (int e0 = base + t; e0 < lim; e0 += 2048) {
        int dd[8];
        #pragma unroll
        for (int q = 0; q < 8; ++q) {
            int e = e0 + q * 256;
            dd[q] = (e < lim) ? ei[E + e] : -1;
        }
        #pragma unroll
        for (int q = 0; q < 8; ++q)
            if (dd[q] >= 0) atomicAdd(&lh[dd[q] >> BSH], 1);
    }
    __syncthreads();
    unsigned short* gh = gchist + (size_t)blockIdx.x * NBUCK;
    for (int b = t; b < NBUCK; b += 256)
        gh[b] = (unsigned short)lh[b];              // c <= EPB=4096, fits ushort
}

// ---------------------------------------------------------------------------
// Kernel: per-(group,bucket) partial sums. Grid = NGRP * (NBUCK/256).
// ---------------------------------------------------------------------------
__launch_bounds__(256)
__global__ void group_sum_kernel(const unsigned short* __restrict__ gchist,
                                 int* __restrict__ psum, int NCH, int CPG) {
    int g  = blockIdx.x >> 2;                       // group
    int br = ((blockIdx.x & 3) << 8) + threadIdx.x; // bucket
    int c0 = g * CPG, c1 = min(NCH, c0 + CPG);
    int s = 0;
    #pragma unroll 4
    for (int c = c0; c < c1; ++c)
        s += (int)gchist[(size_t)c * NBUCK + br];
    psum[(size_t)g * NBUCK + br] = s;
}

// ---------------------------------------------------------------------------
// Kernel: single-block scan over buckets + groups (NGRP values per bucket).
// ---------------------------------------------------------------------------
__launch_bounds__(1024)
__global__ void bucket_scan_kernel(const int* __restrict__ psum,
                                   int* __restrict__ bbase,
                                   int* __restrict__ gbase_grp,
                                   int* __restrict__ offs, int N, int E) {
    __shared__ int s[NBUCK];
    int t = threadIdx.x;
    int v = 0;
    #pragma unroll
    for (int g = 0; g < NGRP; ++g)
        v += psum[(size_t)g * NBUCK + t];
    s[t] = v;
    __syncthreads();
    for (int d = 1; d < NBUCK; d <<= 1) {
        int u = (t >= d) ? s[t - d] : 0;
        __syncthreads();
        s[t] += u;
        __syncthreads();
    }
    int ex = s[t] - v;
    bbase[t] = ex;
    if (t == NBUCK - 1) {
        bbase[NBUCK] = s[t];   // == E
        offs[N] = E;
    }
    int run = ex;
    #pragma unroll
    for (int g = 0; g < NGRP; ++g) {
        gbase_grp[(size_t)g * NBUCK + t] = run;
        run += psum[(size_t)g * NBUCK + t];
    }
}

// ---------------------------------------------------------------------------
// Kernel: per-(chunk,bucket) write bases within each group.
// ---------------------------------------------------------------------------
__launch_bounds__(256)
__global__ void chunk_base_kernel(const unsigned short* __restrict__ gchist,
                                  const int* __restrict__ gbase_grp,
                                  int* __restrict__ gbase, int NCH, int CPG) {
    int g  = blockIdx.x >> 2;
    int br = ((blockIdx.x & 3) << 8) + threadIdx.x;
    int c0 = g * CPG, c1 = min(NCH, c0 + CPG);
    int run = gbase_grp[(size_t)g * NBUCK + br];
    #pragma unroll 4
    for (int c = c0; c < c1; ++c) {
        gbase[(size_t)c * NBUCK + br] = run;
        run += (int)gchist[(size_t)c * NBUCK + br];
    }
}

// ---------------------------------------------------------------------------
// Binning device body: cursor row precomputed from gbase -> single pass,
// LDS atomics only. 8-deep batched. Packed word: src | (dst&127)<<17.
// ---------------------------------------------------------------------------
__device__ inline void binning_body(const int* __restrict__ ei, int E, int chunk,
                                    const int* __restrict__ gbase,
                                    unsigned* __restrict__ ebuf, int* lh) {
    int t = threadIdx.x;
    const int* gb = gbase + (size_t)chunk * NBUCK;
    for (int i = t; i < NBUCK; i += 256) lh[i] = gb[i];
    __syncthreads();
    int base = chunk * EPB;
    int lim  = min(E, base + EPB);
    for (int e0 = base + t; e0 < lim; e0 += 2048) {
        int dd[8], ss[8];
        #pragma unroll
        for (int q = 0; q < 8; ++q) {
            int e = e0 + q * 256;
            if (e < lim) { dd[q] = ei[E + e]; ss[q] = ei[e]; } else dd[q] = -1;
        }
        #pragma unroll
        for (int q = 0; q < 8; ++q) {
            if (dd[q] >= 0) {
                int pos = atomicAdd(&lh[dd[q] >> BSH], 1);
                ebuf[pos] = (unsigned)ss[q] | ((unsigned)(dd[q] & (BW - 1)) << 17);
            }
        }
    }
}

__launch_bounds__(256)
__global__ void binning_kernel(const int* __restrict__ ei, int E,
                               const int* __restrict__ gbase, unsigned* __restrict__ ebuf) {
    __shared__ int lh[NBUCK];
    binning_body(ei, E, blockIdx.x, gbase, ebuf, lh);
}

// Per-j FMA block for the GEMM microkernel (all operands in registers).
#define GEMM_JSTEP(WV, J)                                                    \
    {   float v0 = xa0f[J], v1 = xa1f[J], v2 = xa2f[J], v3 = xa3f[J];        \
        acc0.x = fmaf(v0, WV.x, acc0.x); acc0.y = fmaf(v0, WV.y, acc0.y);    \
        acc0.z = fmaf(v0, WV.z, acc0.z); acc0.w = fmaf(v0, WV.w, acc0.w);    \
        acc1.x = fmaf(v1, WV.x, acc1.x); acc1.y = fmaf(v1, WV.y, acc1.y);    \
        acc1.z = fmaf(v1, WV.z, acc1.z); acc1.w = fmaf(v1, WV.w, acc1.w);    \
        acc2.x = fmaf(v2, WV.x, acc2.x); acc2.y = fmaf(v2, WV.y, acc2.y);    \
        acc2.z = fmaf(v2, WV.z, acc2.z); acc2.w = fmaf(v2, WV.w, acc2.w);    \
        acc3.x = fmaf(v3, WV.x, acc3.x); acc3.y = fmaf(v3, WV.y, acc3.y);    \
        acc3.z = fmaf(v3, WV.z, acc3.z); acc3.w = fmaf(v3, WV.w, acc3.w); }

// ---------------------------------------------------------------------------
// Fused kernel: blocks [0, NBIN) bin; blocks [NBIN, NBIN+G1T) do
// hsb = bf16(x @ W1) for TWO 64-row tiles per block (W1 staged once).
// Per kc, all 8 LDS reads are issued into named registers before any FMA.
// ---------------------------------------------------------------------------
__launch_bounds__(256, 4)
__global__ void gemm1_binning_kernel(const float* __restrict__ x, const float* __restrict__ W1,
                                     unsigned short* __restrict__ hsb,
                                     const int* __restrict__ ei, int E,
                                     const int* __restrict__ gbase, unsigned* __restrict__ ebuf,
                                     int N, int NBIN) {
    __shared__ float smem[FIN * FH + 64 * XSTR];   // 33.8 KB: Ws + Xs | lh (4 KB)
    int tid = threadIdx.x;
    if ((int)blockIdx.x < NBIN) {
        binning_body(ei, E, (int)blockIdx.x, gbase, ebuf, (int*)smem);
        return;
    }
    // ---- GEMM phase: two 64-row tiles ----
    float* Ws = smem;                  // [64][64] row-major (k, col)
    float* Xs = smem + FIN * FH;       // [64][XSTR] row-major (row, k), padded
    int rowBase0 = ((int)blockIdx.x - NBIN) * 128;
    {
        const float4* W14 = (const float4*)W1;
        float4* Ws4 = (float4*)Ws;
        #pragma unroll
        for (int i = tid; i < 1024; i += 256) Ws4[i] = W14[i];
    }
    int cg = tid & 15;                 // col group: cols cg*4..+3
    int rg = tid >> 4;                 // row group: rows rg*4..+3
    const float4* x4 = (const float4*)x;
    ushort4* hsb4 = (ushort4*)hsb;
    for (int h = 0; h < 2; ++h) {
        int rowBase = rowBase0 + h * 64;
        if (rowBase >= N) break;                   // uniform across block
        #pragma unroll
        for (int i = tid; i < 1024; i += 256) {
            int row = i >> 4, kq = i & 15;
            int gr = min(rowBase + row, N - 1);    // clamp: loads never fault
            *(float4*)&Xs[row * XSTR + kq * 4] = x4[(size_t)gr * 16 + kq];
        }
        __syncthreads();
        int r0 = rowBase + rg * 4;
        float4 acc0 = {0,0,0,0}, acc1 = {0,0,0,0}, acc2 = {0,0,0,0}, acc3 = {0,0,0,0};
        #pragma unroll 2
        for (int kc = 0; kc < 16; ++kc) {
            // batch all 8 LDS reads first (single waitcnt), then 256 FMAs
            float4 xa0 = *(const float4*)&Xs[(rg * 4 + 0) * XSTR + kc * 4];
            float4 xa1 = *(const float4*)&Xs[(rg * 4 + 1) * XSTR + kc * 4];
            float4 xa2 = *(const float4*)&Xs[(rg * 4 + 2) * XSTR + kc * 4];
            float4 xa3 = *(const float4*)&Xs[(rg * 4 + 3) * XSTR + kc * 4];
            float4 wv0 = *(const float4*)&Ws[(kc * 4 + 0) * FH + cg * 4];
            float4 wv1 = *(const float4*)&Ws[(kc * 4 + 1) * FH + cg * 4];
            float4 wv2 = *(const float4*)&Ws[(kc * 4 + 2) * FH + cg * 4];
            float4 wv3 = *(const float4*)&Ws[(kc * 4 + 3) * FH + cg * 4];
            const float* xa0f = (const float*)&xa0;
            const float* xa1f = (const float*)&xa1;
            const float* xa2f = (const float*)&xa2;
            const float* xa3f = (const float*)&xa3;
            GEMM_JSTEP(wv0, 0)
            GEMM_JSTEP(wv1, 1)
            GEMM_JSTEP(wv2, 2)
            GEMM_JSTEP(wv3, 3)
        }
        if (r0 + 0 < N) hsb4[(size_t)(r0 + 0) * 16 + cg] =
            make_ushort4(f2bf(acc0.x), f2bf(acc0.y), f2bf(acc0.z), f2bf(acc0.w));
        if (r0 + 1 < N) hsb4[(size_t)(r0 + 1) * 16 + cg] =
            make_ushort4(f2bf(acc1.x), f2bf(acc1.y), f2bf(acc1.z), f2bf(acc1.w));
        if (r0 + 2 < N) hsb4[(size_t)(r0 + 2) * 16 + cg] =
            make_ushort4(f2bf(acc2.x), f2bf(acc2.y), f2bf(acc2.z), f2bf(acc2.w));
        if (r0 + 3 < N) hsb4[(size_t)(r0 + 3) * 16 + cg] =
            make_ushort4(f2bf(acc3.x), f2bf(acc3.y), f2bf(acc3.z), f2bf(acc3.w));
        __syncthreads();                           // Xs reusable next tile
    }
}

// ---------------------------------------------------------------------------
// Kernel: per-bucket CSR build + dinv + offs. One block per bucket; 8-deep
// batched passes; all csr stores land in the block's own contiguous region.
// ---------------------------------------------------------------------------
__launch_bounds__(256)
__global__ void bucket_csr_kernel(const unsigned* __restrict__ ebuf,
                                  const int* __restrict__ bbase,
                                  int* __restrict__ csr, int* __restrict__ offs,
                                  float* __restrict__ dinv, int N) {
    __shared__ int cnt[BW], sc[BW], cur[BW];
    int t = threadIdx.x;
    int b = blockIdx.x;
    if (t < BW) cnt[t] = 0;
    __syncthreads();
    int beg = bbase[b], end = bbase[b + 1];
    for (int i0 = beg + t; i0 < end; i0 += 2048) {
        unsigned ww[8];
        #pragma unroll
        for (int q = 0; q < 8; ++q) {
            int i = i0 + q * 256;
            ww[q] = (i < end) ? ebuf[i] : 0xFFFFFFFFu;   // valid entries < 2^24
        }
        #pragma unroll
        for (int q = 0; q < 8; ++q)
            if (ww[q] != 0xFFFFFFFFu) atomicAdd(&cnt[ww[q] >> 17], 1);
    }
    __syncthreads();
    if (t < BW) sc[t] = cnt[t];
    __syncthreads();
    for (int d = 1; d < BW; d <<= 1) {
        int u = (t < BW && t >= d) ? sc[t - d] : 0;
        __syncthreads();
        if (t < BW) sc[t] += u;
        __syncthreads();
    }
    int nodeBase = b << BSH;
    if (t < BW) {
        int node = nodeBase + t;
        int ex = beg + sc[t] - cnt[t];
        cur[t] = ex;
        if (node < N) {
            offs[node] = ex;
            dinv[node] = rsqrtf((float)(cnt[t] + 1));
        }
    }
    __syncthreads();
    for (int i0 = beg + t; i0 < end; i0 += 2048) {
        unsigned ww[8];
        #pragma unroll
        for (int q = 0; q < 8; ++q) {
            int i = i0 + q * 256;
            ww[q] = (i < end) ? ebuf[i] : 0xFFFFFFFFu;
        }
        #pragma unroll
        for (int q = 0; q < 8; ++q) {
            if (ww[q] != 0xFFFFFFFFu) {
                int pos = atomicAdd(&cur[ww[q] >> 17], 1);
                csr[pos] = (int)(ww[q] & 0x1FFFF);
            }
        }
    }
}

// ---------------------------------------------------------------------------
// Kernel: layer-1 PULL aggregation (bf16 gathers, 8 in flight, per-src dinv
// scale in-reg) fused with finalize1 + GEMM2; writes hs2 pre-scaled as bf16.
// 16 nodes/block; 16 lanes per node, lane owns one ushort4 chunk (4 feats).
// EXACT round-6 body (measured 45-46 us, 0 bank conflicts). All four MLP
// levers failed on this kernel: deeper unroll (R4, +10us), index prefetch
// (R7, +1.5us), lane-split (R8, +17us), dual independent chains (R10,
// +21us). The compiler caps landing registers per chain; ~45 us = ~2 TB/s
// random 128B-gather service from the 12.8 MB table, the practical floor.
// ---------------------------------------------------------------------------
__launch_bounds__(256)
__global__ void agg1_gemm2_kernel(const unsigned short* __restrict__ hsb,
                                  const int* __restrict__ csr,
                                  const int* __restrict__ offs, const float* __restrict__ dinv,
                                  const float* __restrict__ b1, const float* __restrict__ W2,
                                  unsigned short* __restrict__ hs2b, int N) {
    __shared__ float W2s[FH * FO];       // 4 KB
    __shared__ float h1s[16][68];        // 68-float row stride (16B-aligned, non-pow2)
    const ushort4* hs4 = (const ushort4*)hsb;   // 16 ushort4 per row
    int tid = threadIdx.x;
    for (int i = tid; i < FH * FO; i += 256) W2s[i] = W2[i];
    int g = tid >> 4, l = tid & 15;
    int n = blockIdx.x * 16 + g;
    if (n < N) {
        float di_n = dinv[n];
        float4 self = bf4_to_f4(hs4[(size_t)n * 16 + l]);
        float4 acc;
        acc.x = self.x * di_n; acc.y = self.y * di_n;
        acc.z = self.z * di_n; acc.w = self.w * di_n;
        int j = offs[n], end = offs[n + 1];
        for (; j + 7 < end; j += 8) {              // 8 gathers in flight
            int s0 = csr[j],     s1 = csr[j + 1], s2 = csr[j + 2], s3 = csr[j + 3];
            int s4 = csr[j + 4], s5 = csr[j + 5], s6 = csr[j + 6], s7 = csr[j + 7];
            float d0 = dinv[s0], d1 = dinv[s1], d2 = dinv[s2], d3 = dinv[s3];
            float d4 = dinv[s4], d5 = dinv[s5], d6 = dinv[s6], d7 = dinv[s7];
            float4 a0 = bf4_to_f4(hs4[(size_t)s0 * 16 + l]);
            float4 a1 = bf4_to_f4(hs4[(size_t)s1 * 16 + l]);
            float4 a2 = bf4_to_f4(hs4[(size_t)s2 * 16 + l]);
            float4 a3 = bf4_to_f4(hs4[(size_t)s3 * 16 + l]);
            float4 a4 = bf4_to_f4(hs4[(size_t)s4 * 16 + l]);
            float4 a5 = bf4_to_f4(hs4[(size_t)s5 * 16 + l]);
            float4 a6 = bf4_to_f4(hs4[(size_t)s6 * 16 + l]);
            float4 a7 = bf4_to_f4(hs4[(size_t)s7 * 16 + l]);
            acc.x += (fmaf(a0.x, d0, a1.x * d1) + fmaf(a2.x, d2, a3.x * d3))
                   + (fmaf(a4.x, d4, a5.x * d5) + fmaf(a6.x, d6, a7.x * d7));
            acc.y += (fmaf(a0.y, d0, a1.y * d1) + fmaf(a2.y, d2, a3.y * d3))
                   + (fmaf(a4.y, d4, a5.y * d5) + fmaf(a6.y, d6, a7.y * d7));
            acc.z += (fmaf(a0.z, d0, a1.z * d1) + fmaf(a2.z, d2, a3.z * d3))
                   + (fmaf(a4.z, d4, a5.z * d5) + fmaf(a6.z, d6, a7.z * d7));
            acc.w += (fmaf(a0.w, d0, a1.w * d1) + fmaf(a2.w, d2, a3.w * d3))
                   + (fmaf(a4.w, d4, a5.w * d5) + fmaf(a6.w, d6, a7.w * d7));
        }
        for (; j + 1 < end; j += 2) {
            int s0 = csr[j], s1 = csr[j + 1];
            float d0 = dinv[s0], d1 = dinv[s1];
            float4 a0 = bf4_to_f4(hs4[(size_t)s0 * 16 + l]);
            float4 a1 = bf4_to_f4(hs4[(size_t)s1 * 16 + l]);
            acc.x += fmaf(a0.x, d0, a1.x * d1);
            acc.y += fmaf(a0.y, d0, a1.y * d1);
            acc.z += fmaf(a0.z, d0, a1.z * d1);
            acc.w += fmaf(a0.w, d0, a1.w * d1);
        }
        if (j < end) {
            int s0 = csr[j];
            float d0 = dinv[s0];
            float4 a0 = bf4_to_f4(hs4[(size_t)s0 * 16 + l]);
            acc.x = fmaf(a0.x, d0, acc.x); acc.y = fmaf(a0.y, d0, acc.y);
            acc.z = fmaf(a0.z, d0, acc.z); acc.w = fmaf(a0.w, d0, acc.w);
        }
        float4 bb = ((const float4*)b1)[l];
        float4 h;
        h.x = fmaxf(fmaf(di_n, acc.x, bb.x), 0.f);
        h.y = fmaxf(fmaf(di_n, acc.y, bb.y), 0.f);
        h.z = fmaxf(fmaf(di_n, acc.z, bb.z), 0.f);
        h.w = fmaxf(fmaf(di_n, acc.w, bb.w), 0.f);
        *((float4*)&h1s[g][l * 4]) = h;
    }
    __syncthreads();
    int r = tid >> 4, o = tid & 15;     // 16 rows x 16 out-cols
    int n2 = blockIdx.x * 16 + r;
    if (n2 < N) {
        float acc = 0.f;
        #pragma unroll
        for (int jj = 0; jj < FH; ++jj)
            acc = fmaf(h1s[r][jj], W2s[jj * FO + o], acc);
        hs2b[(size_t)n2 * FO + o] = f2bf(acc * dinv[n2]);   // pre-scaled bf16
    }
}

// ---------------------------------------------------------------------------
// Kernel: layer-2 PULL aggregation (8 gathers in flight) + bias + log_softmax.
// hs2b table is 3.2 MB -> fits per-XCD L2; gathers are 2B/lane.
// ---------------------------------------------------------------------------
__launch_bounds__(256)
__global__ void agg2_softmax_kernel(const unsigned short* __restrict__ hs2b,
                                    const int* __restrict__ csr,
                                    const int* __restrict__ offs, const float* __restrict__ dinv,
                                    const float* __restrict__ b2, float* __restrict__ out, int N) {
    int tid = threadIdx.x;
    int g = tid >> 4, o = tid & 15;
    int n = blockIdx.x * 16 + g;
    float v = 0.f;
    if (n < N) {
        float acc = bf2f(hs2b[(size_t)n * 16 + o]);    // self loop (pre-scaled)
        int j = offs[n], end = offs[n + 1];
        for (; j + 7 < end; j += 8) {
            int s0 = csr[j],     s1 = csr[j + 1], s2 = csr[j + 2], s3 = csr[j + 3];
            int s4 = csr[j + 4], s5 = csr[j + 5], s6 = csr[j + 6], s7 = csr[j + 7];
            float t0 = bf2f(hs2b[(size_t)s0 * 16 + o]) + bf2f(hs2b[(size_t)s1 * 16 + o]);
            float t1 = bf2f(hs2b[(size_t)s2 * 16 + o]) + bf2f(hs2b[(size_t)s3 * 16 + o]);
            float t2 = bf2f(hs2b[(size_t)s4 * 16 + o]) + bf2f(hs2b[(size_t)s5 * 16 + o]);
            float t3 = bf2f(hs2b[(size_t)s6 * 16 + o]) + bf2f(hs2b[(size_t)s7 * 16 + o]);
            acc += (t0 + t1) + (t2 + t3);
        }
        for (; j < end; ++j) acc += bf2f(hs2b[(size_t)csr[j] * 16 + o]);
        v = fmaf(dinv[n], acc, b2[o]);
    }
    float m = v;
    #pragma unroll
    for (int s = 8; s >= 1; s >>= 1) m = fmaxf(m, __shfl_xor(m, s, 64));
    float ex = __expf(v - m);
    float sum = ex;
    #pragma unroll
    for (int s = 8; s >= 1; s >>= 1) sum += __shfl_xor(sum, s, 64);
    if (n < N) out[(size_t)n * FO + o] = v - m - __logf(sum);
}

// ---------------------------------------------------------------------------
extern "C" void kernel_launch(void* const* d_in, const int* in_sizes, int n_in,
                              void* d_out, int out_size, void* d_ws, size_t ws_size,
                              hipStream_t stream) {
    const float* x  = (const float*)d_in[0];
    const int*   ei = (const int*)d_in[1];     // int32
    const float* W1 = (const float*)d_in[2];
    const float* b1 = (const float*)d_in[3];
    const float* W2 = (const float*)d_in[4];
    const float* b2 = (const float*)d_in[5];
    float* out = (float*)d_out;

    const int N = in_sizes[0] / FIN;
    const int E = in_sizes[1] / 2;
    const int NCH  = (E + EPB - 1) / EPB;            // hist/binning chunks
    const int CPG  = (NCH + NGRP - 1) / NGRP;        // chunks per scan-group
    const int NB4  = (N + BW - 1) / BW;              // buckets actually used
    const int G1T  = (N + 127) / 128;                // gemm 128-row (2-tile) blocks
    const int GA   = (N + 15) / 16;                  // agg blocks

    char* ws = (char*)d_ws;
    size_t off = 0;
    auto alloc = [&](size_t bytes) -> void* {
        off = (off + 255) & ~(size_t)255;
        void* p = ws + off;
        off += bytes;
        return p;
    };
    float*          dinv      = (float*)alloc((size_t)N * 4);               //  0.4 MB
    unsigned short* hsb       = (unsigned short*)alloc((size_t)N * FH * 2); // 12.8 MB
    unsigned short* hs2b      = (unsigned short*)alloc((size_t)N * FO * 2); //  3.2 MB
    int*            offs      = (int*)alloc((size_t)(N + 1) * 4);           //  0.4 MB
    int*            bbase     = (int*)alloc((NBUCK + 1) * 4);
    unsigned short* gchist    = (unsigned short*)alloc((size_t)NCH * NBUCK * 2); // 0.8 MB
    int*            gbase     = (int*)alloc((size_t)NCH * NBUCK * 4);       //  1.6 MB
    int*            psum      = (int*)alloc((size_t)NGRP * NBUCK * 4);      //  128 KB
    int*            gbase_grp = (int*)alloc((size_t)NGRP * NBUCK * 4);      //  128 KB
    // ebuf + csr (2*E ints = 12.8 MB): in ws if it fits, else alias the x
    // input buffer (25.6 MB, dead after the gemm phase; harness restores d_in
    // before every launch; ws_size constant -> capture-stable branch).
    unsigned* ebuf;
    int*      csr;
    bool ws_fits = (ws_size >= off + 512 + (size_t)E * 8);
    if (ws_fits) {
        ebuf = (unsigned*)alloc((size_t)E * 4);
        csr  = (int*)     alloc((size_t)E * 4);
    } else {
        ebuf = (unsigned*)x;
        csr  = (int*)x + E;
    }

    hist_kernel<<<NCH, 256, 0, stream>>>(ei, E, gchist);
    group_sum_kernel<<<NGRP * (NBUCK / 256), 256, 0, stream>>>(gchist, psum, NCH, CPG);
    bucket_scan_kernel<<<1, NBUCK, 0, stream>>>(psum, bbase, gbase_grp, offs, N, E);
    chunk_base_kernel<<<NGRP * (NBUCK / 256), 256, 0, stream>>>(gchist, gbase_grp,
                                                                gbase, NCH, CPG);
    if (ws_fits) {
        // Overlap: binning blocks first, gemm blocks backfill.
        gemm1_binning_kernel<<<NCH + G1T, 256, 0, stream>>>(x, W1, hsb, ei, E,
                                                            gbase, ebuf, N, NCH);
    } else {
        // ebuf aliases x: gemm must fully precede binning.
        gemm1_binning_kernel<<<G1T, 256, 0, stream>>>(x, W1, hsb, ei, E,
                                                      gbase, ebuf, N, 0);
        binning_kernel<<<NCH, 256, 0, stream>>>(ei, E, gbase, ebuf);
    }
    bucket_csr_kernel<<<NB4, 256, 0, stream>>>(ebuf, bbase, csr, offs, dinv, N);
    agg1_gemm2_kernel<<<GA, 256, 0, stream>>>(hsb, csr, offs, dinv, b1, W2, hs2b, N);
    agg2_softmax_kernel<<<GA, 256, 0, stream>>>(hs2b, csr, offs, dinv, b2, out, N);
}